// Round 3
// baseline (256.400 us; speedup 1.0000x reference)
//
#include <hip/hip_runtime.h>
#include <math.h>

// ---------------------------------------------------------------------------
// NFFT forward (type-2): f_hat (B,C,256,256 complex) -> samples at M points.
// Pipeline: deconvolve+pad+fftshift -> 2D FFT 512x512 -> windowed gather.
// Shift algebra: ifftshift(FFT(fftshift(p)))[(ind+256)%512] == FFT(fftshift(p))[ind%512],
// so the single shift folds into staging and the gather reads X[ind & 511].
// Output written PLANAR: real plane (B,C,M) then imag plane (complex ref is
// compared as concatenated real/imag; interleaved .view layout gave the
// round-2 permutation-mismatch signature absmax~1700).
// ---------------------------------------------------------------------------

#define NGRID 512          // oversampled grid (per dim)
#define NSMALL 256         // N grid (per dim)
#define MW 4               // window half-width m
#define BB 2
#define CC 2
#define MPTS 200000
#define PLANE (BB * CC * MPTS)   // offset of imag plane in floats

// I0(z) asymptotic series, valid z > 8 (our z in [17.7, 18.9])
__device__ __forceinline__ float nfft29781_i0_large(float z) {
    float inv = 1.0f / z;
    float p = 1.0f + inv * (0.125f + inv * (0.0703125f
              + inv * (0.0732421875f + inv * 0.112152099609375f)));
    return expf(z) * rsqrtf(2.0f * (float)M_PI * z) * p;
}

// ---------------------------------------------------------------------------
// Stage nimg images starting at global image img0 into G (local layout:
// image i of this launch at G + i*512*512). Writes ALL elements (zeros
// outside support) so no workspace memset is needed.
// ---------------------------------------------------------------------------
__global__ __launch_bounds__(256) void nfft29781_stage(const float* __restrict__ fr,
                                                       const float* __restrict__ fi,
                                                       float2* __restrict__ G,
                                                       int img0, int nimg) {
    int t = blockIdx.x * blockDim.x + threadIdx.x;
    if (t >= nimg * NGRID * NGRID) return;
    int j2 = t & (NGRID - 1);
    int j1 = (t >> 9) & (NGRID - 1);
    int img = img0 + (t >> 18);

    float2 v = make_float2(0.0f, 0.0f);
    int a1 = -1, a2 = -1;   // f_hat indices after fftshift-fold
    if (j1 < 128) a1 = j1 + 128; else if (j1 >= 384) a1 = j1 - 384;
    if (j2 < 128) a2 = j2 + 128; else if (j2 >= 384) a2 = j2 - 384;
    if (a1 >= 0 && a2 >= 0) {
        const float bcon = 1.5f * (float)M_PI;
        const float scale = 2.0f * (float)M_PI / (float)NGRID;
        float k1 = (float)(a1 - 128) * scale;
        float k2 = (float)(a2 - 128) * scale;
        float ph = nfft29781_i0_large((float)MW * sqrtf(bcon * bcon - k1 * k1))
                 * nfft29781_i0_large((float)MW * sqrtf(bcon * bcon - k2 * k2));
        size_t src = ((size_t)img * NSMALL + a1) * NSMALL + a2;
        float s = 1.0f / ph;
        v.x = fr[src] * s;
        v.y = fi[src] * s;
    }
    G[t] = v;
}

// ---------------------------------------------------------------------------
// 512-point radix-2 DIT FFT in LDS. 256 threads, one butterfly per stage.
// Input loaded in bit-reversed order. Forward DFT (e^{-2pi i jk/n}).
// ---------------------------------------------------------------------------
__device__ __forceinline__ void nfft29781_fft512(float2* s, int tid) {
    #pragma unroll
    for (int st = 0; st < 9; ++st) {
        int half = 1 << st;
        int pos = tid & (half - 1);
        int i0 = ((tid >> st) << (st + 1)) + pos;
        int i1 = i0 + half;
        float ang = -(float)M_PI * (float)pos / (float)half;
        float sn, cs;
        sincosf(ang, &sn, &cs);
        float2 a = s[i0];
        float2 b = s[i1];
        float2 tw = make_float2(b.x * cs - b.y * sn, b.x * sn + b.y * cs);
        s[i0] = make_float2(a.x + tw.x, a.y + tw.y);
        s[i1] = make_float2(a.x - tw.x, a.y - tw.y);
        __syncthreads();
    }
}

__global__ __launch_bounds__(256) void nfft29781_fft_rows(float2* __restrict__ G) {
    __shared__ float2 s[NGRID];
    size_t base = (size_t)blockIdx.x * NGRID;   // one block per row
    int tid = threadIdx.x;
    s[__brev((unsigned)tid) >> 23] = G[base + tid];
    s[__brev((unsigned)(tid + 256)) >> 23] = G[base + tid + 256];
    __syncthreads();
    nfft29781_fft512(s, tid);
    G[base + tid] = s[tid];
    G[base + tid + 256] = s[tid + 256];
}

__global__ __launch_bounds__(256) void nfft29781_fft_cols(float2* __restrict__ G) {
    __shared__ float2 s[NGRID];
    int col = blockIdx.x & (NGRID - 1);
    int img = blockIdx.x >> 9;                  // local image index
    size_t base = (size_t)img * NGRID * NGRID + col;
    int tid = threadIdx.x;
    s[__brev((unsigned)tid) >> 23] = G[base + (size_t)tid * NGRID];
    s[__brev((unsigned)(tid + 256)) >> 23] = G[base + (size_t)(tid + 256) * NGRID];
    __syncthreads();
    nfft29781_fft512(s, tid);
    G[base + (size_t)tid * NGRID] = s[tid];
    G[base + (size_t)(tid + 256) * NGRID] = s[tid + 256];
}

// ---------------------------------------------------------------------------
// Kaiser-Bessel per-dim weights for one point coordinate.
// ---------------------------------------------------------------------------
__device__ __forceinline__ void nfft29781_weights(float u, int& base, float* w) {
    float c = ceilf(u);
    base = (int)c - MW;
    float d = c - u;
    const float bw = 1.5f * (float)M_PI;
    const float invpi = 1.0f / (float)M_PI;
    #pragma unroll
    for (int i = 0; i < 8; ++i) {
        float nk = (float)(MW - i) - d;
        float tt = (float)(MW * MW) - nk * nk;
        float wv = 0.0f;
        if (tt > 0.0f) {
            float a = sqrtf(tt);
            float e = expf(bw * a);
            wv = (e - 1.0f / e) * 0.5f * invpi / a;
        }
        w[i] = wv;
    }
}

// Full gather: both channels of both batches in one launch. G holds 4 images.
__global__ __launch_bounds__(256) void nfft29781_gather_full(const float* __restrict__ x,
                                                             const float2* __restrict__ G,
                                                             float* __restrict__ out,
                                                             int out_elems) {
    int t = blockIdx.x * blockDim.x + threadIdx.x;
    if (t >= BB * MPTS) return;
    int b = t / MPTS;
    int pt = t - b * MPTS;

    float u0 = x[(size_t)(b * MPTS + pt) * 2 + 0] * (float)NGRID;
    float u1 = x[(size_t)(b * MPTS + pt) * 2 + 1] * (float)NGRID;
    int base0, base1;
    float w0[8], w1[8];
    nfft29781_weights(u0, base0, w0);
    nfft29781_weights(u1, base1, w1);

    const float2* G0 = G + (size_t)(b * CC + 0) * NGRID * NGRID;
    const float2* G1 = G + (size_t)(b * CC + 1) * NGRID * NGRID;
    float2 acc0 = make_float2(0.0f, 0.0f);
    float2 acc1 = make_float2(0.0f, 0.0f);
    #pragma unroll
    for (int i = 0; i < 8; ++i) {
        float wi = w0[i];
        int rowoff = ((base0 + i) & (NGRID - 1)) * NGRID;
        #pragma unroll
        for (int j = 0; j < 8; ++j) {
            float w = wi * w1[j];
            int cix = (base1 + j) & (NGRID - 1);
            float2 g0 = G0[rowoff + cix];
            float2 g1 = G1[rowoff + cix];
            acc0.x += w * g0.x; acc0.y += w * g0.y;
            acc1.x += w * g1.x; acc1.y += w * g1.y;
        }
    }
    size_t o0 = (size_t)(b * CC + 0) * MPTS + pt;
    size_t o1 = (size_t)(b * CC + 1) * MPTS + pt;
    // PLANAR: real plane then imag plane
    if (o0 < (size_t)out_elems)         out[o0]         = acc0.x;
    if (PLANE + o0 < (size_t)out_elems) out[PLANE + o0] = acc0.y;
    if (o1 < (size_t)out_elems)         out[o1]         = acc1.x;
    if (PLANE + o1 < (size_t)out_elems) out[PLANE + o1] = acc1.y;
}

// Per-image gather: one channel of one batch; G holds a single image.
__global__ __launch_bounds__(256) void nfft29781_gather_one(const float* __restrict__ x,
                                                            const float2* __restrict__ G,
                                                            float* __restrict__ out,
                                                            int img, int out_elems) {
    int pt = blockIdx.x * blockDim.x + threadIdx.x;
    if (pt >= MPTS) return;
    int b = img / CC;

    float u0 = x[(size_t)(b * MPTS + pt) * 2 + 0] * (float)NGRID;
    float u1 = x[(size_t)(b * MPTS + pt) * 2 + 1] * (float)NGRID;
    int base0, base1;
    float w0[8], w1[8];
    nfft29781_weights(u0, base0, w0);
    nfft29781_weights(u1, base1, w1);

    float2 acc = make_float2(0.0f, 0.0f);
    #pragma unroll
    for (int i = 0; i < 8; ++i) {
        float wi = w0[i];
        int rowoff = ((base0 + i) & (NGRID - 1)) * NGRID;
        #pragma unroll
        for (int j = 0; j < 8; ++j) {
            float w = wi * w1[j];
            int cix = (base1 + j) & (NGRID - 1);
            float2 g = G[rowoff + cix];
            acc.x += w * g.x; acc.y += w * g.y;
        }
    }
    size_t o = (size_t)img * MPTS + pt;
    // PLANAR: real plane then imag plane
    if (o < (size_t)out_elems)         out[o]         = acc.x;
    if (PLANE + o < (size_t)out_elems) out[PLANE + o] = acc.y;
}

extern "C" void kernel_launch(void* const* d_in, const int* in_sizes, int n_in,
                              void* d_out, int out_size, void* d_ws, size_t ws_size,
                              hipStream_t stream) {
    (void)in_sizes; (void)n_in;
    const float* x  = (const float*)d_in[0];
    const float* fr = (const float*)d_in[1];
    const float* fi = (const float*)d_in[2];
    float* out = (float*)d_out;
    float2* G  = (float2*)d_ws;

    const size_t imgBytes  = (size_t)NGRID * NGRID * sizeof(float2);   // 2 MB
    const size_t fullBytes = (size_t)BB * CC * imgBytes;               // 8 MB

    if (ws_size >= fullBytes) {
        int total = BB * CC * NGRID * NGRID;
        nfft29781_stage<<<(total + 255) / 256, 256, 0, stream>>>(fr, fi, G, 0, BB * CC);
        nfft29781_fft_rows<<<BB * CC * NGRID, 256, 0, stream>>>(G);
        nfft29781_fft_cols<<<BB * CC * NGRID, 256, 0, stream>>>(G);
        nfft29781_gather_full<<<(BB * MPTS + 255) / 256, 256, 0, stream>>>(x, G, out, out_size);
    } else if (ws_size >= imgBytes) {
        for (int img = 0; img < BB * CC; ++img) {
            int total = NGRID * NGRID;
            nfft29781_stage<<<(total + 255) / 256, 256, 0, stream>>>(fr, fi, G, img, 1);
            nfft29781_fft_rows<<<NGRID, 256, 0, stream>>>(G);
            nfft29781_fft_cols<<<NGRID, 256, 0, stream>>>(G);
            nfft29781_gather_one<<<(MPTS + 255) / 256, 256, 0, stream>>>(x, G, out, img, out_size);
        }
    }
    // else: workspace too small for any path — intentional no-op so the bench
    // reports absmax == max|ref| (diagnostic) instead of a memory fault.
}